// Round 10
// baseline (78.763 us; speedup 1.0000x reference)
//
#include <hip/hip_runtime.h>
#include <hip/hip_bf16.h>

#define EPSV 1e-8f
#define WSTRIDE 516   // floats; %4==0 (b128-aligned columns), %32==4 (bank spread)

typedef float f32x4 __attribute__((ext_vector_type(4)));

__device__ __forceinline__ float rdlane(float v, int l) {
    return __int_as_float(__builtin_amdgcn_readlane(__float_as_int(v), l));
}

__device__ __forceinline__ void load_w_row(const float* __restrict__ lip_w,
                                           const float* __restrict__ pose_w,
                                           int row, float* w) {
    const float4* lp4 = reinterpret_cast<const float4*>(lip_w + row * 20);
    float4 t0 = lp4[0], t1 = lp4[1], t2 = lp4[2], t3 = lp4[3], t4 = lp4[4];
    const float2* pp2 = reinterpret_cast<const float2*>(pose_w + row * 6);
    float2 u0 = pp2[0], u1 = pp2[1], u2 = pp2[2];
    w[0]  = t0.x + EPSV; w[1]  = t0.y + EPSV; w[2]  = t0.z + EPSV; w[3]  = t0.w + EPSV;
    w[4]  = t1.x + EPSV; w[5]  = t1.y + EPSV; w[6]  = t1.z + EPSV; w[7]  = t1.w + EPSV;
    w[8]  = t2.x + EPSV; w[9]  = t2.y + EPSV; w[10] = t2.z + EPSV; w[11] = t2.w + EPSV;
    w[12] = t3.x + EPSV; w[13] = t3.y + EPSV; w[14] = t3.z + EPSV; w[15] = t3.w + EPSV;
    w[16] = t4.x + EPSV; w[17] = t4.y + EPSV; w[18] = t4.z + EPSV; w[19] = t4.w + EPSV;
    w[20] = u0.x + EPSV; w[21] = u0.y + EPSV;
    w[22] = u1.x + EPSV; w[23] = u1.y + EPSV;
    w[24] = u2.x + EPSV; w[25] = u2.y + EPSV;
}

// ---------------------------------------------------------------------------
// Collapsed Householder step J on the 26x26 pivot block (Gram invariant).
// Lane c owns column c of P (pivot rows) and R; cross-lane via v_readlane.
// ---------------------------------------------------------------------------
template<int J>
struct QRStep {
    static __device__ __forceinline__ void run(float (&P)[26], float (&R)[26],
                                               const float (&Gr)[26], const int tid) {
        float sig = rdlane(Gr[J], J);          // G[J][J]
        float dot = 0.f;                        // sum_{i<J} R[i][J] * R[i][c]
#pragma unroll
        for (int i = 0; i < 26; ++i) {
            if (i < J) {
                const float rij = rdlane(R[i], J);
                sig = fmaf(-rij, rij, sig);
                dot = fmaf(rij, R[i], dot);
            }
        }
        const float alpha  = rdlane(P[J], J);
        const float S      = Gr[J] - dot - alpha * P[J];
        const float normx  = sqrtf(sig);
        const float beta   = (alpha >= 0.f) ? -normx : normx;   // LAPACK slarfg
        const float tau    = (beta - alpha) / beta;
        const float rdenom = 1.f / (alpha - beta);
        const float dc     = fmaf(S, rdenom, P[J]);
        R[J] = (tid == J) ? beta : fmaf(-tau, dc, P[J]);        // R row J
        const float trd = tau * rdenom;
#pragma unroll
        for (int i = 0; i < 26; ++i) {
            if (i > J) {
                const float pij = rdlane(P[i], J);              // P[i][J]
                P[i] = fmaf(-(trd * pij), dc, P[i]);
            }
        }
    }
};

template<int J> struct QRSteps {
    static __device__ __forceinline__ void run(float (&P)[26], float (&R)[26],
                                               const float (&Gr)[26], int tid) {
        QRStep<J>::run(P, R, Gr, tid);
        QRSteps<J + 1>::run(P, R, Gr, tid);
    }
};
template<> struct QRSteps<26> {
    static __device__ __forceinline__ void run(float (&)[26], float (&)[26],
                                               const float (&)[26], int) {}
};

__global__ __launch_bounds__(512) void qr_kernel(const float* __restrict__ pose_w,
                                                 const float* __restrict__ lip_w,
                                                 float* __restrict__ qt) {
    __shared__ float Wc[26 * WSTRIDE];    // W+EPS, column-major
    __shared__ float Gp[8][26][27];       // per-wave partial Gram
    __shared__ float G[26 * 27 + 8];      // Gram (both triangles)
    __shared__ float Rlds[26][27];
    __shared__ float Rinv[26][27];

    const int tid  = threadIdx.x;
    const int lane = tid & 63;
    const int wid  = tid >> 6;

    // ---- Stage 1: load row tid, scatter to column-major LDS --------------
    {
        float w[26];
        load_w_row(lip_w, pose_w, tid, w);
#pragma unroll
        for (int c = 0; c < 26; ++c) Wc[c * WSTRIDE + tid] = w[c];
    }
    __syncthreads();

    // ---- Stage 2: Gram G = W^T W, 8-wave parallel over row chunks --------
    if (lane < 45) {
        int tm = 0, rem = lane;
        while (rem >= 9 - tm) { rem -= 9 - tm; ++tm; }
        const int tn = tm + rem;
        const int ra = (tm * 3 > 23) ? 23 : tm * 3;   // clamped tiles overlap but
        const int ca = (tn * 3 > 23) ? 23 : tn * 3;   // write identical values
        const f32x4* A0 = reinterpret_cast<const f32x4*>(&Wc[(ra + 0) * WSTRIDE]);
        const f32x4* A1 = reinterpret_cast<const f32x4*>(&Wc[(ra + 1) * WSTRIDE]);
        const f32x4* A2 = reinterpret_cast<const f32x4*>(&Wc[(ra + 2) * WSTRIDE]);
        const f32x4* B0 = reinterpret_cast<const f32x4*>(&Wc[(ca + 0) * WSTRIDE]);
        const f32x4* B1 = reinterpret_cast<const f32x4*>(&Wc[(ca + 1) * WSTRIDE]);
        const f32x4* B2 = reinterpret_cast<const f32x4*>(&Wc[(ca + 2) * WSTRIDE]);
        float acc[3][3] = {{0.f, 0.f, 0.f}, {0.f, 0.f, 0.f}, {0.f, 0.f, 0.f}};
        const int i0 = 16 * wid;
#pragma unroll 4
        for (int ii = 0; ii < 16; ++ii) {
            const int i = i0 + ii;
            const f32x4 av[3] = {A0[i], A1[i], A2[i]};
            const f32x4 bv[3] = {B0[i], B1[i], B2[i]};
#pragma unroll
            for (int r = 0; r < 3; ++r) {
#pragma unroll
                for (int c = 0; c < 3; ++c) {
                    acc[r][c] = fmaf(av[r].x, bv[c].x, acc[r][c]);
                    acc[r][c] = fmaf(av[r].y, bv[c].y, acc[r][c]);
                    acc[r][c] = fmaf(av[r].z, bv[c].z, acc[r][c]);
                    acc[r][c] = fmaf(av[r].w, bv[c].w, acc[r][c]);
                }
            }
        }
#pragma unroll
        for (int r = 0; r < 3; ++r) {
#pragma unroll
            for (int c = 0; c < 3; ++c) {
                Gp[wid][ra + r][ca + c] = acc[r][c];
                Gp[wid][ca + c][ra + r] = acc[r][c];
            }
        }
    }
    __syncthreads();

    // Reduce the 8 partials: thread t < 351 owns upper-tri pair (r,c).
    if (tid < 351) {
        int r = 0, t = tid;
        while (t >= 26 - r) { t -= 26 - r; ++r; }
        const int c = r + t;
        float s = 0.f;
#pragma unroll
        for (int w8 = 0; w8 < 8; ++w8) s += Gp[w8][r][c];
        G[r * 27 + c] = s;
        G[c * 27 + r] = s;
    }
    __syncthreads();

    // ---- Stage 3: 26-step collapsed Householder + back-sub (wave 0) -----
    if (tid < 64) {
        const int cc = (tid < 26) ? tid : 25;   // clamp for safe addressing
        float P[26], R[26], Gr[26];
        {   // column cc, rows 0..25, via 7 b128 reads (stride WSTRIDE%4==0)
            const f32x4* pc = reinterpret_cast<const f32x4*>(&Wc[cc * WSTRIDE]);
            const f32x4 q0 = pc[0], q1 = pc[1], q2 = pc[2], q3 = pc[3],
                        q4 = pc[4], q5 = pc[5], q6 = pc[6];
            P[0]=q0.x;  P[1]=q0.y;  P[2]=q0.z;  P[3]=q0.w;
            P[4]=q1.x;  P[5]=q1.y;  P[6]=q1.z;  P[7]=q1.w;
            P[8]=q2.x;  P[9]=q2.y;  P[10]=q2.z; P[11]=q2.w;
            P[12]=q3.x; P[13]=q3.y; P[14]=q3.z; P[15]=q3.w;
            P[16]=q4.x; P[17]=q4.y; P[18]=q4.z; P[19]=q4.w;
            P[20]=q5.x; P[21]=q5.y; P[22]=q5.z; P[23]=q5.w;
            P[24]=q6.x; P[25]=q6.y;
        }
#pragma unroll
        for (int j = 0; j < 26; ++j) Gr[j] = G[j * 27 + cc];

        QRSteps<0>::run(P, R, Gr, tid);

        // Stage R (lane c holds column c); same-wave write->read is ordered.
        if (tid < 26) {
#pragma unroll
            for (int i = 0; i < 26; ++i)
                if (i <= tid) Rlds[i][tid] = R[i];
        }

        // Back-substitution: thread cc solves column cc of R^{-1}.
        if (tid < 26) {
            float ri[26];
#pragma unroll
            for (int k = 25; k >= 0; --k) {
                float s = (k == tid) ? 1.f : 0.f;
#pragma unroll
                for (int m = 25; m > k; --m)
                    if (m <= tid) s = fmaf(-Rlds[k][m], ri[m], s);
                ri[k] = s / Rlds[k][k];
            }
#pragma unroll
            for (int k = 0; k < 26; ++k)
                if (k <= tid) Rinv[k][tid] = ri[k];
        }
    }
    __syncthreads();

    // ---- Stage 4: Q = W * Rinv, transposed store qt[k*512 + row] ---------
    if (tid < 128) {
        float w0[26], w1[26], w2[26], w3[26];
        load_w_row(lip_w, pose_w, tid,       w0);
        load_w_row(lip_w, pose_w, tid + 128, w1);
        load_w_row(lip_w, pose_w, tid + 256, w2);
        load_w_row(lip_w, pose_w, tid + 384, w3);
#pragma unroll
        for (int k = 0; k < 26; ++k) {
            float q0 = 0.f, q1 = 0.f, q2 = 0.f, q3 = 0.f;
#pragma unroll
            for (int m = 0; m < 26; ++m) {
                if (m <= k) {
                    const float r = Rinv[m][k];
                    q0 = fmaf(w0[m], r, q0);
                    q1 = fmaf(w1[m], r, q1);
                    q2 = fmaf(w2[m], r, q2);
                    q3 = fmaf(w3[m], r, q3);
                }
            }
            float* qk = qt + k * 512 + tid;
            qk[0]   = q0;
            qk[128] = q1;
            qk[256] = q2;
            qk[384] = q3;
        }
    }
}

// ---------------------------------------------------------------------------
// out[B][512] = input[B][26] @ qt^T   (qt is [26][512])
// Round-6 store geometry (4096 blocks, 32-row tile, rh-split, NT f32x4
// stores) with ONE change: the x values are wave-uniform, so they are read
// via SCALAR loads (SMEM/K$) from a readfirstlane-hoisted uniform pointer —
// no LDS staging, no scatter, no __syncthreads, zero LDS/VMEM traffic for x.
// ---------------------------------------------------------------------------

__global__ __launch_bounds__(256) void out_gemm(const float* __restrict__ in,
                                                const float* __restrict__ qt,
                                                float* __restrict__ out) {
    const int tid = threadIdx.x;
    const int cg  = tid & 127;            // column group: cols 4*cg .. 4*cg+3
    const int rh  = tid >> 7;             // row half: 0 or 1 (wave-uniform)
    const long base = (long)blockIdx.x * 32;

    f32x4 qf[26];
#pragma unroll
    for (int k = 0; k < 26; ++k)
        qf[k] = *reinterpret_cast<const f32x4*>(qt + k * 512 + cg * 4);

    // Wave-uniform base offset for this wave's 16 rows (elements; fits i32:
    // max = 131072*26 = 3.4M). readfirstlane -> SGPR -> scalar loads.
    const int woff = __builtin_amdgcn_readfirstlane((int)(base + rh * 16) * 26);
    // Row pitch 26 floats = 104 B; 8 | 104, so float2 chunks stay 8B-aligned.
    const float2* __restrict__ xr2 = reinterpret_cast<const float2*>(in + woff);

    float* op = out + (base + (long)rh * 16) * 512 + cg * 4;
#pragma unroll
    for (int r = 0; r < 16; ++r) {
        float xv[26];
#pragma unroll
        for (int j = 0; j < 13; ++j) {
            const float2 t = xr2[r * 13 + j];
            xv[2 * j]     = t.x;
            xv[2 * j + 1] = t.y;
        }
        f32x4 acc = {0.f, 0.f, 0.f, 0.f};
#pragma unroll
        for (int k = 0; k < 26; ++k) {
            acc.x = fmaf(xv[k], qf[k].x, acc.x);
            acc.y = fmaf(xv[k], qf[k].y, acc.y);
            acc.z = fmaf(xv[k], qf[k].z, acc.z);
            acc.w = fmaf(xv[k], qf[k].w, acc.w);
        }
        __builtin_nontemporal_store(acc,
            reinterpret_cast<f32x4*>(op + (long)r * 512));
    }
}

// ---------------------------------------------------------------------------

extern "C" void kernel_launch(void* const* d_in, const int* in_sizes, int n_in,
                              void* d_out, int out_size, void* d_ws, size_t ws_size,
                              hipStream_t stream) {
    const float* input  = (const float*)d_in[0];   // (B, 26)
    const float* pose_w = (const float*)d_in[1];   // (512, 6)
    const float* lip_w  = (const float*)d_in[2];   // (512, 20)
    float* out = (float*)d_out;                    // (B, 512)
    float* qt  = (float*)d_ws;                     // Q^T as [26][512] f32

    const int B = in_sizes[0] / 26;

    qr_kernel<<<1, 512, 0, stream>>>(pose_w, lip_w, qt);
    out_gemm<<<(B + 31) / 32, 256, 0, stream>>>(input, qt, out);
}

// Round 11
// 72.860 us; speedup vs baseline: 1.0810x; 1.0810x over previous
//
#include <hip/hip_runtime.h>
#include <hip/hip_bf16.h>

#define EPSV 1e-8f
#define WSTRIDE 516   // floats; %4==0 (b128-aligned columns), %32==4 (bank spread)

typedef float f32x4 __attribute__((ext_vector_type(4)));
typedef float f32x2 __attribute__((ext_vector_type(2)));

__device__ __forceinline__ float rdlane(float v, int l) {
    return __int_as_float(__builtin_amdgcn_readlane(__float_as_int(v), l));
}

__device__ __forceinline__ void load_w_row(const float* __restrict__ lip_w,
                                           const float* __restrict__ pose_w,
                                           int row, float* w) {
    const float4* lp4 = reinterpret_cast<const float4*>(lip_w + row * 20);
    float4 t0 = lp4[0], t1 = lp4[1], t2 = lp4[2], t3 = lp4[3], t4 = lp4[4];
    const float2* pp2 = reinterpret_cast<const float2*>(pose_w + row * 6);
    float2 u0 = pp2[0], u1 = pp2[1], u2 = pp2[2];
    w[0]  = t0.x + EPSV; w[1]  = t0.y + EPSV; w[2]  = t0.z + EPSV; w[3]  = t0.w + EPSV;
    w[4]  = t1.x + EPSV; w[5]  = t1.y + EPSV; w[6]  = t1.z + EPSV; w[7]  = t1.w + EPSV;
    w[8]  = t2.x + EPSV; w[9]  = t2.y + EPSV; w[10] = t2.z + EPSV; w[11] = t2.w + EPSV;
    w[12] = t3.x + EPSV; w[13] = t3.y + EPSV; w[14] = t3.z + EPSV; w[15] = t3.w + EPSV;
    w[16] = t4.x + EPSV; w[17] = t4.y + EPSV; w[18] = t4.z + EPSV; w[19] = t4.w + EPSV;
    w[20] = u0.x + EPSV; w[21] = u0.y + EPSV;
    w[22] = u1.x + EPSV; w[23] = u1.y + EPSV;
    w[24] = u2.x + EPSV; w[25] = u2.y + EPSV;
}

// ---------------------------------------------------------------------------
// Collapsed Householder step J on the 26x26 pivot block (Gram invariant).
// Lane c owns column c of P (pivot rows) and R; cross-lane via v_readlane.
// ---------------------------------------------------------------------------
template<int J>
struct QRStep {
    static __device__ __forceinline__ void run(float (&P)[26], float (&R)[26],
                                               const float (&Gr)[26], const int tid) {
        float sig = rdlane(Gr[J], J);          // G[J][J]
        float dot = 0.f;                        // sum_{i<J} R[i][J] * R[i][c]
#pragma unroll
        for (int i = 0; i < 26; ++i) {
            if (i < J) {
                const float rij = rdlane(R[i], J);
                sig = fmaf(-rij, rij, sig);
                dot = fmaf(rij, R[i], dot);
            }
        }
        const float alpha  = rdlane(P[J], J);
        const float S      = Gr[J] - dot - alpha * P[J];
        const float normx  = sqrtf(sig);
        const float beta   = (alpha >= 0.f) ? -normx : normx;   // LAPACK slarfg
        const float tau    = (beta - alpha) / beta;
        const float rdenom = 1.f / (alpha - beta);
        const float dc     = fmaf(S, rdenom, P[J]);
        R[J] = (tid == J) ? beta : fmaf(-tau, dc, P[J]);        // R row J
        const float trd = tau * rdenom;
#pragma unroll
        for (int i = 0; i < 26; ++i) {
            if (i > J) {
                const float pij = rdlane(P[i], J);              // P[i][J]
                P[i] = fmaf(-(trd * pij), dc, P[i]);
            }
        }
    }
};

template<int J> struct QRSteps {
    static __device__ __forceinline__ void run(float (&P)[26], float (&R)[26],
                                               const float (&Gr)[26], int tid) {
        QRStep<J>::run(P, R, Gr, tid);
        QRSteps<J + 1>::run(P, R, Gr, tid);
    }
};
template<> struct QRSteps<26> {
    static __device__ __forceinline__ void run(float (&)[26], float (&)[26],
                                               const float (&)[26], int) {}
};

__global__ __launch_bounds__(512) void qr_kernel(const float* __restrict__ pose_w,
                                                 const float* __restrict__ lip_w,
                                                 float* __restrict__ qt) {
    __shared__ float Wc[26 * WSTRIDE];    // W+EPS, column-major
    __shared__ float Gp[8][26][27];       // per-wave partial Gram
    __shared__ float G[26 * 27 + 8];      // Gram (both triangles)
    __shared__ float Rlds[26][27];
    __shared__ float Rinv[26][27];

    const int tid  = threadIdx.x;
    const int lane = tid & 63;
    const int wid  = tid >> 6;

    // ---- Stage 1: load row tid, scatter to column-major LDS --------------
    {
        float w[26];
        load_w_row(lip_w, pose_w, tid, w);
#pragma unroll
        for (int c = 0; c < 26; ++c) Wc[c * WSTRIDE + tid] = w[c];
    }
    __syncthreads();

    // ---- Stage 2: Gram G = W^T W, 8-wave parallel over row chunks --------
    if (lane < 45) {
        int tm = 0, rem = lane;
        while (rem >= 9 - tm) { rem -= 9 - tm; ++tm; }
        const int tn = tm + rem;
        const int ra = (tm * 3 > 23) ? 23 : tm * 3;   // clamped tiles overlap but
        const int ca = (tn * 3 > 23) ? 23 : tn * 3;   // write identical values
        const f32x4* A0 = reinterpret_cast<const f32x4*>(&Wc[(ra + 0) * WSTRIDE]);
        const f32x4* A1 = reinterpret_cast<const f32x4*>(&Wc[(ra + 1) * WSTRIDE]);
        const f32x4* A2 = reinterpret_cast<const f32x4*>(&Wc[(ra + 2) * WSTRIDE]);
        const f32x4* B0 = reinterpret_cast<const f32x4*>(&Wc[(ca + 0) * WSTRIDE]);
        const f32x4* B1 = reinterpret_cast<const f32x4*>(&Wc[(ca + 1) * WSTRIDE]);
        const f32x4* B2 = reinterpret_cast<const f32x4*>(&Wc[(ca + 2) * WSTRIDE]);
        float acc[3][3] = {{0.f, 0.f, 0.f}, {0.f, 0.f, 0.f}, {0.f, 0.f, 0.f}};
        const int i0 = 16 * wid;
#pragma unroll 4
        for (int ii = 0; ii < 16; ++ii) {
            const int i = i0 + ii;
            const f32x4 av[3] = {A0[i], A1[i], A2[i]};
            const f32x4 bv[3] = {B0[i], B1[i], B2[i]};
#pragma unroll
            for (int r = 0; r < 3; ++r) {
#pragma unroll
                for (int c = 0; c < 3; ++c) {
                    acc[r][c] = fmaf(av[r].x, bv[c].x, acc[r][c]);
                    acc[r][c] = fmaf(av[r].y, bv[c].y, acc[r][c]);
                    acc[r][c] = fmaf(av[r].z, bv[c].z, acc[r][c]);
                    acc[r][c] = fmaf(av[r].w, bv[c].w, acc[r][c]);
                }
            }
        }
#pragma unroll
        for (int r = 0; r < 3; ++r) {
#pragma unroll
            for (int c = 0; c < 3; ++c) {
                Gp[wid][ra + r][ca + c] = acc[r][c];
                Gp[wid][ca + c][ra + r] = acc[r][c];
            }
        }
    }
    __syncthreads();

    // Reduce the 8 partials: thread t < 351 owns upper-tri pair (r,c).
    if (tid < 351) {
        int r = 0, t = tid;
        while (t >= 26 - r) { t -= 26 - r; ++r; }
        const int c = r + t;
        float s = 0.f;
#pragma unroll
        for (int w8 = 0; w8 < 8; ++w8) s += Gp[w8][r][c];
        G[r * 27 + c] = s;
        G[c * 27 + r] = s;
    }
    __syncthreads();

    // ---- Stage 3: 26-step collapsed Householder + back-sub (wave 0) -----
    if (tid < 64) {
        const int cc = (tid < 26) ? tid : 25;   // clamp for safe addressing
        float P[26], R[26], Gr[26];
        {   // column cc, rows 0..25, via 7 b128 reads (stride WSTRIDE%4==0)
            const f32x4* pc = reinterpret_cast<const f32x4*>(&Wc[cc * WSTRIDE]);
            const f32x4 q0 = pc[0], q1 = pc[1], q2 = pc[2], q3 = pc[3],
                        q4 = pc[4], q5 = pc[5], q6 = pc[6];
            P[0]=q0.x;  P[1]=q0.y;  P[2]=q0.z;  P[3]=q0.w;
            P[4]=q1.x;  P[5]=q1.y;  P[6]=q1.z;  P[7]=q1.w;
            P[8]=q2.x;  P[9]=q2.y;  P[10]=q2.z; P[11]=q2.w;
            P[12]=q3.x; P[13]=q3.y; P[14]=q3.z; P[15]=q3.w;
            P[16]=q4.x; P[17]=q4.y; P[18]=q4.z; P[19]=q4.w;
            P[20]=q5.x; P[21]=q5.y; P[22]=q5.z; P[23]=q5.w;
            P[24]=q6.x; P[25]=q6.y;
        }
#pragma unroll
        for (int j = 0; j < 26; ++j) Gr[j] = G[j * 27 + cc];

        QRSteps<0>::run(P, R, Gr, tid);

        // Stage R (lane c holds column c); same-wave write->read is ordered.
        if (tid < 26) {
#pragma unroll
            for (int i = 0; i < 26; ++i)
                if (i <= tid) Rlds[i][tid] = R[i];
        }

        // Back-substitution: thread cc solves column cc of R^{-1}.
        if (tid < 26) {
            float ri[26];
#pragma unroll
            for (int k = 25; k >= 0; --k) {
                float s = (k == tid) ? 1.f : 0.f;
#pragma unroll
                for (int m = 25; m > k; --m)
                    if (m <= tid) s = fmaf(-Rlds[k][m], ri[m], s);
                ri[k] = s / Rlds[k][k];
            }
#pragma unroll
            for (int k = 0; k < 26; ++k)
                if (k <= tid) Rinv[k][tid] = ri[k];
        }
    }
    __syncthreads();

    // ---- Stage 4: Q = W * Rinv, transposed store qt[k*512 + row] ---------
    if (tid < 128) {
        float w0[26], w1[26], w2[26], w3[26];
        load_w_row(lip_w, pose_w, tid,       w0);
        load_w_row(lip_w, pose_w, tid + 128, w1);
        load_w_row(lip_w, pose_w, tid + 256, w2);
        load_w_row(lip_w, pose_w, tid + 384, w3);
#pragma unroll
        for (int k = 0; k < 26; ++k) {
            float q0 = 0.f, q1 = 0.f, q2 = 0.f, q3 = 0.f;
#pragma unroll
            for (int m = 0; m < 26; ++m) {
                if (m <= k) {
                    const float r = Rinv[m][k];
                    q0 = fmaf(w0[m], r, q0);
                    q1 = fmaf(w1[m], r, q1);
                    q2 = fmaf(w2[m], r, q2);
                    q3 = fmaf(w3[m], r, q3);
                }
            }
            float* qk = qt + k * 512 + tid;
            qk[0]   = q0;
            qk[128] = q1;
            qk[256] = q2;
            qk[384] = q3;
        }
    }
}

// ---------------------------------------------------------------------------
// out[B][512] = input[B][26] @ qt^T   (qt is [26][512])
// EXACT round-6 structure (4096 blocks, 32-row tile, padded LDS, b128 row
// reads, rh-split, NT f32x4 stores) with ONE change: the inner product uses
// PACKED f32x2 FMAs (v_pk_fma_f32 via __builtin_elementwise_fma) — 52 packed
// ops/row instead of 104 scalar v_fma_f32, halving VALU issue per wave and
// freeing issue slots to hide qf-load / LDS / store latency.
// ---------------------------------------------------------------------------

__global__ __launch_bounds__(256) void out_gemm(const float* __restrict__ in,
                                                const float* __restrict__ qt,
                                                float* __restrict__ out) {
    __shared__ __align__(16) float xs[32 * 28];
    const int tid = threadIdx.x;
    const long base = (long)blockIdx.x * 32;

    // Stage 32x26 tile: 208 threads load f32x4, scatter 4 elements each into
    // the padded layout (div-by-26 compiles to magic-mul).
    if (tid < 208) {
        const float4 v = reinterpret_cast<const float4*>(in + base * 26)[tid];
        const float vals[4] = {v.x, v.y, v.z, v.w};
        const int e0 = tid * 4;
#pragma unroll
        for (int q = 0; q < 4; ++q) {
            const int e = e0 + q;
            const int r = e / 26;
            const int c = e - r * 26;
            xs[r * 28 + c] = vals[q];
        }
    }

    const int cg = tid & 127;             // column group: cols 4*cg .. 4*cg+3
    const int rh = tid >> 7;              // row half: 0 or 1

    // Q fragment as packed pairs (same 104 VGPRs as f32x4[26]).
    f32x2 qA[26], qB[26];
#pragma unroll
    for (int k = 0; k < 26; ++k) {
        const f32x4 t = *reinterpret_cast<const f32x4*>(qt + k * 512 + cg * 4);
        qA[k].x = t.x; qA[k].y = t.y;
        qB[k].x = t.z; qB[k].y = t.w;
    }
    __syncthreads();

    float* op = out + (base + (long)rh * 16) * 512 + cg * 4;
#pragma unroll
    for (int r = 0; r < 16; ++r) {
        const float* xr = xs + (rh * 16 + r) * 28;
        const f32x4 t0 = *reinterpret_cast<const f32x4*>(xr + 0);
        const f32x4 t1 = *reinterpret_cast<const f32x4*>(xr + 4);
        const f32x4 t2 = *reinterpret_cast<const f32x4*>(xr + 8);
        const f32x4 t3 = *reinterpret_cast<const f32x4*>(xr + 12);
        const f32x4 t4 = *reinterpret_cast<const f32x4*>(xr + 16);
        const f32x4 t5 = *reinterpret_cast<const f32x4*>(xr + 20);
        const f32x4 t6 = *reinterpret_cast<const f32x4*>(xr + 24);  // .z/.w unused
        float xv[26];
        xv[0]=t0.x;  xv[1]=t0.y;  xv[2]=t0.z;  xv[3]=t0.w;
        xv[4]=t1.x;  xv[5]=t1.y;  xv[6]=t1.z;  xv[7]=t1.w;
        xv[8]=t2.x;  xv[9]=t2.y;  xv[10]=t2.z; xv[11]=t2.w;
        xv[12]=t3.x; xv[13]=t3.y; xv[14]=t3.z; xv[15]=t3.w;
        xv[16]=t4.x; xv[17]=t4.y; xv[18]=t4.z; xv[19]=t4.w;
        xv[20]=t5.x; xv[21]=t5.y; xv[22]=t5.z; xv[23]=t5.w;
        xv[24]=t6.x; xv[25]=t6.y;

        f32x2 a01 = {0.f, 0.f}, a23 = {0.f, 0.f};
#pragma unroll
        for (int k = 0; k < 26; ++k) {
            f32x2 xk; xk.x = xv[k]; xk.y = xv[k];
            a01 = __builtin_elementwise_fma(xk, qA[k], a01);   // v_pk_fma_f32
            a23 = __builtin_elementwise_fma(xk, qB[k], a23);   // v_pk_fma_f32
        }
        f32x4 acc;
        acc.x = a01.x; acc.y = a01.y; acc.z = a23.x; acc.w = a23.y;
        __builtin_nontemporal_store(acc,
            reinterpret_cast<f32x4*>(op + (long)r * 512));
    }
}

// ---------------------------------------------------------------------------

extern "C" void kernel_launch(void* const* d_in, const int* in_sizes, int n_in,
                              void* d_out, int out_size, void* d_ws, size_t ws_size,
                              hipStream_t stream) {
    const float* input  = (const float*)d_in[0];   // (B, 26)
    const float* pose_w = (const float*)d_in[1];   // (512, 6)
    const float* lip_w  = (const float*)d_in[2];   // (512, 20)
    float* out = (float*)d_out;                    // (B, 512)
    float* qt  = (float*)d_ws;                     // Q^T as [26][512] f32

    const int B = in_sizes[0] / 26;

    qr_kernel<<<1, 512, 0, stream>>>(pose_w, lip_w, qt);
    out_gemm<<<(B + 31) / 32, 256, 0, stream>>>(input, qt, out);
}

// Round 12
// 72.202 us; speedup vs baseline: 1.0909x; 1.0091x over previous
//
#include <hip/hip_runtime.h>
#include <hip/hip_bf16.h>

#define EPSV 1e-8f
#define WSTRIDE 516   // floats; %4==0 (b128-aligned columns), %32==4 (bank spread)

typedef float f32x4 __attribute__((ext_vector_type(4)));

__device__ __forceinline__ float rdlane(float v, int l) {
    return __int_as_float(__builtin_amdgcn_readlane(__float_as_int(v), l));
}

__device__ __forceinline__ void load_w_row(const float* __restrict__ lip_w,
                                           const float* __restrict__ pose_w,
                                           int row, float* w) {
    const float4* lp4 = reinterpret_cast<const float4*>(lip_w + row * 20);
    float4 t0 = lp4[0], t1 = lp4[1], t2 = lp4[2], t3 = lp4[3], t4 = lp4[4];
    const float2* pp2 = reinterpret_cast<const float2*>(pose_w + row * 6);
    float2 u0 = pp2[0], u1 = pp2[1], u2 = pp2[2];
    w[0]  = t0.x + EPSV; w[1]  = t0.y + EPSV; w[2]  = t0.z + EPSV; w[3]  = t0.w + EPSV;
    w[4]  = t1.x + EPSV; w[5]  = t1.y + EPSV; w[6]  = t1.z + EPSV; w[7]  = t1.w + EPSV;
    w[8]  = t2.x + EPSV; w[9]  = t2.y + EPSV; w[10] = t2.z + EPSV; w[11] = t2.w + EPSV;
    w[12] = t3.x + EPSV; w[13] = t3.y + EPSV; w[14] = t3.z + EPSV; w[15] = t3.w + EPSV;
    w[16] = t4.x + EPSV; w[17] = t4.y + EPSV; w[18] = t4.z + EPSV; w[19] = t4.w + EPSV;
    w[20] = u0.x + EPSV; w[21] = u0.y + EPSV;
    w[22] = u1.x + EPSV; w[23] = u1.y + EPSV;
    w[24] = u2.x + EPSV; w[25] = u2.y + EPSV;
}

// ---------------------------------------------------------------------------
// Collapsed Householder step J, Cholesky-assisted.
// Lane c owns: P[·] (pivot-block column c), Gt[·] (Gram column c, trailing
// Schur maintained in-place), R[·] (output R column c).
// Identities (signs of R rows cancel in squares):
//   sigma_J            = Rc[J,J]^2            (Rc = chol factor, pos diag)
//   Sum_{i<J} R R      = Sum_{i<J} Rc Rc  ==> S_c = Rc[J,J]*Rc[J,c] - a*P[J,c]
// Per step: 1 rsq + 2 rcp, (26-J) independent readlane+fma for the chol
// update, (26-J) for the P update. No serial dot-loop, no sqrt/div chains.
// ---------------------------------------------------------------------------
template<int J>
struct QRStep {
    static __device__ __forceinline__ void run(float (&P)[26], float (&Gt)[26],
                                               float (&R)[26], const int tid) {
        // --- Cholesky step J ---
        const float dJ2  = rdlane(Gt[J], J);              // trailing diag
        const float invd = __builtin_amdgcn_rsqf(dJ2);
        const float dJ   = dJ2 * invd;                    // = sqrt(dJ2)
        const float rcj  = (tid >= J) ? Gt[J] * invd : 0.f;   // Rc[J,c]
#pragma unroll
        for (int i = 0; i < 26; ++i)
            if (i > J) Gt[i] = fmaf(-rdlane(rcj, i), rcj, Gt[i]);

        // --- Householder sign recursion (P = pivot block) ---
        const float alpha = rdlane(P[J], J);
        const float beta  = (alpha >= 0.f) ? -dJ : dJ;    // LAPACK slarfg
        const float bma   = beta - alpha;
        const float tau   = bma * __builtin_amdgcn_rcpf(beta);
        const float rdn   = -__builtin_amdgcn_rcpf(bma);  // 1/(alpha-beta)
        const float S     = fmaf(dJ, rcj, -(alpha * P[J]));
        const float dc    = fmaf(S, rdn, P[J]);
        R[J] = (tid == J) ? beta : fmaf(-tau, dc, P[J]);  // R row J
        const float trd = tau * rdn;
#pragma unroll
        for (int i = 0; i < 26; ++i)
            if (i > J) P[i] = fmaf(-(trd * rdlane(P[i], J)), dc, P[i]);
    }
};

template<int J> struct QRSteps {
    static __device__ __forceinline__ void run(float (&P)[26], float (&Gt)[26],
                                               float (&R)[26], int tid) {
        QRStep<J>::run(P, Gt, R, tid);
        QRSteps<J + 1>::run(P, Gt, R, tid);
    }
};
template<> struct QRSteps<26> {
    static __device__ __forceinline__ void run(float (&)[26], float (&)[26],
                                               float (&)[26], int) {}
};

__global__ __launch_bounds__(512) void qr_kernel(const float* __restrict__ pose_w,
                                                 const float* __restrict__ lip_w,
                                                 float* __restrict__ qt) {
    __shared__ float Wc[26 * WSTRIDE];    // W+EPS, column-major
    __shared__ float Gp[8][26][27];       // per-wave partial Gram
    __shared__ float G[26 * 27 + 8];      // Gram (both triangles)
    __shared__ float Rlds[26][27];
    __shared__ float Rinv[26][27];

    const int tid  = threadIdx.x;
    const int lane = tid & 63;
    const int wid  = tid >> 6;

    // ---- Stage 1: load row tid, scatter to column-major LDS --------------
    {
        float w[26];
        load_w_row(lip_w, pose_w, tid, w);
#pragma unroll
        for (int c = 0; c < 26; ++c) Wc[c * WSTRIDE + tid] = w[c];
    }
    __syncthreads();

    // ---- Stage 2: Gram G = W^T W, 8-wave parallel over row chunks --------
    if (lane < 45) {
        int tm = 0, rem = lane;
        while (rem >= 9 - tm) { rem -= 9 - tm; ++tm; }
        const int tn = tm + rem;
        const int ra = (tm * 3 > 23) ? 23 : tm * 3;   // clamped tiles overlap but
        const int ca = (tn * 3 > 23) ? 23 : tn * 3;   // write identical values
        const f32x4* A0 = reinterpret_cast<const f32x4*>(&Wc[(ra + 0) * WSTRIDE]);
        const f32x4* A1 = reinterpret_cast<const f32x4*>(&Wc[(ra + 1) * WSTRIDE]);
        const f32x4* A2 = reinterpret_cast<const f32x4*>(&Wc[(ra + 2) * WSTRIDE]);
        const f32x4* B0 = reinterpret_cast<const f32x4*>(&Wc[(ca + 0) * WSTRIDE]);
        const f32x4* B1 = reinterpret_cast<const f32x4*>(&Wc[(ca + 1) * WSTRIDE]);
        const f32x4* B2 = reinterpret_cast<const f32x4*>(&Wc[(ca + 2) * WSTRIDE]);
        float acc[3][3] = {{0.f, 0.f, 0.f}, {0.f, 0.f, 0.f}, {0.f, 0.f, 0.f}};
        const int i0 = 16 * wid;
#pragma unroll 4
        for (int ii = 0; ii < 16; ++ii) {
            const int i = i0 + ii;
            const f32x4 av[3] = {A0[i], A1[i], A2[i]};
            const f32x4 bv[3] = {B0[i], B1[i], B2[i]};
#pragma unroll
            for (int r = 0; r < 3; ++r) {
#pragma unroll
                for (int c = 0; c < 3; ++c) {
                    acc[r][c] = fmaf(av[r].x, bv[c].x, acc[r][c]);
                    acc[r][c] = fmaf(av[r].y, bv[c].y, acc[r][c]);
                    acc[r][c] = fmaf(av[r].z, bv[c].z, acc[r][c]);
                    acc[r][c] = fmaf(av[r].w, bv[c].w, acc[r][c]);
                }
            }
        }
#pragma unroll
        for (int r = 0; r < 3; ++r) {
#pragma unroll
            for (int c = 0; c < 3; ++c) {
                Gp[wid][ra + r][ca + c] = acc[r][c];
                Gp[wid][ca + c][ra + r] = acc[r][c];
            }
        }
    }
    __syncthreads();

    // Reduce the 8 partials: thread t < 351 owns upper-tri pair (r,c).
    if (tid < 351) {
        int r = 0, t = tid;
        while (t >= 26 - r) { t -= 26 - r; ++r; }
        const int c = r + t;
        float s = 0.f;
#pragma unroll
        for (int w8 = 0; w8 < 8; ++w8) s += Gp[w8][r][c];
        G[r * 27 + c] = s;
        G[c * 27 + r] = s;
    }
    __syncthreads();

    // ---- Stage 3: chol-assisted 26-step Householder + back-sub (wave 0) --
    if (tid < 64) {
        const int cc = (tid < 26) ? tid : 25;   // clamp for safe addressing
        float P[26], Gt[26], R[26];
        {   // pivot column cc, rows 0..25, via 7 b128 reads
            const f32x4* pc = reinterpret_cast<const f32x4*>(&Wc[cc * WSTRIDE]);
            const f32x4 q0 = pc[0], q1 = pc[1], q2 = pc[2], q3 = pc[3],
                        q4 = pc[4], q5 = pc[5], q6 = pc[6];
            P[0]=q0.x;  P[1]=q0.y;  P[2]=q0.z;  P[3]=q0.w;
            P[4]=q1.x;  P[5]=q1.y;  P[6]=q1.z;  P[7]=q1.w;
            P[8]=q2.x;  P[9]=q2.y;  P[10]=q2.z; P[11]=q2.w;
            P[12]=q3.x; P[13]=q3.y; P[14]=q3.z; P[15]=q3.w;
            P[16]=q4.x; P[17]=q4.y; P[18]=q4.z; P[19]=q4.w;
            P[20]=q5.x; P[21]=q5.y; P[22]=q5.z; P[23]=q5.w;
            P[24]=q6.x; P[25]=q6.y;
        }
#pragma unroll
        for (int j = 0; j < 26; ++j) Gt[j] = G[j * 27 + cc];

        QRSteps<0>::run(P, Gt, R, tid);

        // Stage R (lane c holds column c); same-wave write->read is ordered.
        if (tid < 26) {
#pragma unroll
            for (int i = 0; i < 26; ++i)
                if (i <= tid) Rlds[i][tid] = R[i];
        }

        // Back-substitution: thread cc solves column cc of R^{-1} (rcp div).
        if (tid < 26) {
            float ri[26];
#pragma unroll
            for (int k = 25; k >= 0; --k) {
                float s = (k == tid) ? 1.f : 0.f;
#pragma unroll
                for (int m = 25; m > k; --m)
                    if (m <= tid) s = fmaf(-Rlds[k][m], ri[m], s);
                ri[k] = s * __builtin_amdgcn_rcpf(Rlds[k][k]);
            }
#pragma unroll
            for (int k = 0; k < 26; ++k)
                if (k <= tid) Rinv[k][tid] = ri[k];
        }
    }
    __syncthreads();

    // ---- Stage 4: Q = W * Rinv, transposed store qt[k*512 + row] ---------
    if (tid < 128) {
        float w0[26], w1[26], w2[26], w3[26];
        load_w_row(lip_w, pose_w, tid,       w0);
        load_w_row(lip_w, pose_w, tid + 128, w1);
        load_w_row(lip_w, pose_w, tid + 256, w2);
        load_w_row(lip_w, pose_w, tid + 384, w3);
#pragma unroll
        for (int k = 0; k < 26; ++k) {
            float q0 = 0.f, q1 = 0.f, q2 = 0.f, q3 = 0.f;
#pragma unroll
            for (int m = 0; m < 26; ++m) {
                if (m <= k) {
                    const float r = Rinv[m][k];
                    q0 = fmaf(w0[m], r, q0);
                    q1 = fmaf(w1[m], r, q1);
                    q2 = fmaf(w2[m], r, q2);
                    q3 = fmaf(w3[m], r, q3);
                }
            }
            float* qk = qt + k * 512 + tid;
            qk[0]   = q0;
            qk[128] = q1;
            qk[256] = q2;
            qk[384] = q3;
        }
    }
}

// ---------------------------------------------------------------------------
// out[B][512] = input[B][26] @ qt^T   (qt is [26][512])
// BYTE-IDENTICAL to round 6 (best measured: 72.8): 4096 independent blocks,
// 32-row padded LDS tile, b128 row reads, rh-split, NT f32x4 stores.
// ---------------------------------------------------------------------------

__global__ __launch_bounds__(256) void out_gemm(const float* __restrict__ in,
                                                const float* __restrict__ qt,
                                                float* __restrict__ out) {
    __shared__ __align__(16) float xs[32 * 28];
    const int tid = threadIdx.x;
    const long base = (long)blockIdx.x * 32;

    if (tid < 208) {
        const float4 v = reinterpret_cast<const float4*>(in + base * 26)[tid];
        const float vals[4] = {v.x, v.y, v.z, v.w};
        const int e0 = tid * 4;
#pragma unroll
        for (int q = 0; q < 4; ++q) {
            const int e = e0 + q;
            const int r = e / 26;
            const int c = e - r * 26;
            xs[r * 28 + c] = vals[q];
        }
    }

    const int cg = tid & 127;             // column group: cols 4*cg .. 4*cg+3
    const int rh = tid >> 7;              // row half: 0 or 1

    f32x4 qf[26];
#pragma unroll
    for (int k = 0; k < 26; ++k)
        qf[k] = *reinterpret_cast<const f32x4*>(qt + k * 512 + cg * 4);
    __syncthreads();

    float* op = out + (base + (long)rh * 16) * 512 + cg * 4;
#pragma unroll
    for (int r = 0; r < 16; ++r) {
        const float* xr = xs + (rh * 16 + r) * 28;
        const f32x4 t0 = *reinterpret_cast<const f32x4*>(xr + 0);
        const f32x4 t1 = *reinterpret_cast<const f32x4*>(xr + 4);
        const f32x4 t2 = *reinterpret_cast<const f32x4*>(xr + 8);
        const f32x4 t3 = *reinterpret_cast<const f32x4*>(xr + 12);
        const f32x4 t4 = *reinterpret_cast<const f32x4*>(xr + 16);
        const f32x4 t5 = *reinterpret_cast<const f32x4*>(xr + 20);
        const f32x4 t6 = *reinterpret_cast<const f32x4*>(xr + 24);  // .z/.w unused
        float xv[26];
        xv[0]=t0.x;  xv[1]=t0.y;  xv[2]=t0.z;  xv[3]=t0.w;
        xv[4]=t1.x;  xv[5]=t1.y;  xv[6]=t1.z;  xv[7]=t1.w;
        xv[8]=t2.x;  xv[9]=t2.y;  xv[10]=t2.z; xv[11]=t2.w;
        xv[12]=t3.x; xv[13]=t3.y; xv[14]=t3.z; xv[15]=t3.w;
        xv[16]=t4.x; xv[17]=t4.y; xv[18]=t4.z; xv[19]=t4.w;
        xv[20]=t5.x; xv[21]=t5.y; xv[22]=t5.z; xv[23]=t5.w;
        xv[24]=t6.x; xv[25]=t6.y;
        f32x4 acc = {0.f, 0.f, 0.f, 0.f};
#pragma unroll
        for (int k = 0; k < 26; ++k) {
            acc.x = fmaf(xv[k], qf[k].x, acc.x);
            acc.y = fmaf(xv[k], qf[k].y, acc.y);
            acc.z = fmaf(xv[k], qf[k].z, acc.z);
            acc.w = fmaf(xv[k], qf[k].w, acc.w);
        }
        __builtin_nontemporal_store(acc,
            reinterpret_cast<f32x4*>(op + (long)r * 512));
    }
}

// ---------------------------------------------------------------------------

extern "C" void kernel_launch(void* const* d_in, const int* in_sizes, int n_in,
                              void* d_out, int out_size, void* d_ws, size_t ws_size,
                              hipStream_t stream) {
    const float* input  = (const float*)d_in[0];   // (B, 26)
    const float* pose_w = (const float*)d_in[1];   // (512, 6)
    const float* lip_w  = (const float*)d_in[2];   // (512, 20)
    float* out = (float*)d_out;                    // (B, 512)
    float* qt  = (float*)d_ws;                     // Q^T as [26][512] f32

    const int B = in_sizes[0] / 26;

    qr_kernel<<<1, 512, 0, stream>>>(pose_w, lip_w, qt);
    out_gemm<<<(B + 31) / 32, 256, 0, stream>>>(input, qt, out);
}